// Round 2
// baseline (711.038 us; speedup 1.0000x reference)
//
#include <hip/hip_runtime.h>
#include <stdint.h>

typedef unsigned short u16;

#define GAS __attribute__((address_space(1)))
#define LAS __attribute__((address_space(3)))

typedef __bf16 bf16x8 __attribute__((ext_vector_type(8)));
typedef float f32x4 __attribute__((ext_vector_type(4)));

// B=4, T=2048, D_IN=D_OUT=2048. M = 8192, K = 6144, N = 2048.
// All inputs/outputs fp32. GEMM internally bf16 MFMA.
// ws layout: Z bf16 [8192 x 6144] (96 MB) | Wcat bf16 [2048 x 6144] (24 MB)

__device__ inline u16 f2b(float f) {
    uint32_t x = __float_as_uint(f);
    uint32_t r = (x + 0x7fffu + ((x >> 16) & 1u)) >> 16;
    return (u16)r;
}

__device__ inline float b2f(u16 u) {
    union { uint32_t i; float f; } v;
    v.i = ((uint32_t)u) << 16;
    return v.f;
}

__device__ inline void load8b(float* v, const u16* p) {
    uint4 u = *(const uint4*)p;
    v[0] = b2f((u16)(u.x)); v[1] = b2f((u16)(u.x >> 16));
    v[2] = b2f((u16)(u.y)); v[3] = b2f((u16)(u.y >> 16));
    v[4] = b2f((u16)(u.z)); v[5] = b2f((u16)(u.z >> 16));
    v[6] = b2f((u16)(u.w)); v[7] = b2f((u16)(u.w >> 16));
}

__device__ inline void load8f(float* v, const float* p) {
    float4 a = *(const float4*)p;
    float4 b = *(const float4*)(p + 4);
    v[0] = a.x; v[1] = a.y; v[2] = a.z; v[3] = a.w;
    v[4] = b.x; v[5] = b.y; v[6] = b.z; v[7] = b.w;
}

__device__ inline void store8b(u16* p, const float* v, float scale) {
    uint4 u;
    u.x = (uint32_t)f2b(v[0] * scale) | ((uint32_t)f2b(v[1] * scale) << 16);
    u.y = (uint32_t)f2b(v[2] * scale) | ((uint32_t)f2b(v[3] * scale) << 16);
    u.z = (uint32_t)f2b(v[4] * scale) | ((uint32_t)f2b(v[5] * scale) << 16);
    u.w = (uint32_t)f2b(v[6] * scale) | ((uint32_t)f2b(v[7] * scale) << 16);
    *(uint4*)p = u;
}

// ---------------------------------------------------------------------------
// Kernel 0: pack Wp|Wi|Wd (fp32) into Wcat bf16 rows of 6144.
// ---------------------------------------------------------------------------
__global__ __launch_bounds__(256) void pack_w(
    const float* __restrict__ Wp, const float* __restrict__ Wi,
    const float* __restrict__ Wd, u16* __restrict__ Wcat)
{
    int i = (blockIdx.x * 256 + threadIdx.x) * 8;   // over 3*4M elements
    int seg = i >> 22;                               // 4M per matrix
    int j = i & 4194303;
    const float* src = (seg == 0) ? Wp : (seg == 1) ? Wi : Wd;
    int o = j >> 11;
    int c = j & 2047;
    float v[8];
    load8f(v, src + j);
    store8b(Wcat + (size_t)o * 6144 + seg * 2048 + c, v, 1.0f);
}

// ---------------------------------------------------------------------------
// Kernel 1: per-(b,d) scan over T. fp32 x -> bf16 s,d in Z segs 1,2.
// ---------------------------------------------------------------------------
__global__ __launch_bounds__(64) void scan_kernel(
    const float* __restrict__ x, const float* __restrict__ alog,
    const float* __restrict__ blog, u16* __restrict__ Z)
{
    int g = blockIdx.x * 64 + threadIdx.x;   // 0..8191
    int b = g >> 11;
    int d = g & 2047;
    float alpha = 1.f / (1.f + __expf(-alog[d]));
    float beta  = 1.f / (1.f + __expf(-blog[d]));
    float oma = 1.f - alpha, omb = 1.f - beta;
    const float* xp = x + ((size_t)b * 2048) * 2048 + d;
    u16* zp = Z + ((size_t)b * 2048) * 6144 + 2048 + d;
    float s = 0.f, dd = 0.f, xprev = 0.f;
    #pragma unroll 16
    for (int t = 0; t < 2048; ++t) {
        float xf = xp[(size_t)t * 2048];
        s = alpha * s + oma * xf;
        dd = beta * dd + omb * (xf - xprev);
        xprev = xf;
        size_t zo = (size_t)t * 6144;
        zp[zo] = f2b(s);
        zp[zo + 2048] = f2b(dd);
    }
}

// ---------------------------------------------------------------------------
// Kernel 2: per-row gate logits + softmax; write Z row = [g0*x|g1*s|g2*d] bf16.
// One block (256 thr) per row.
// ---------------------------------------------------------------------------
__global__ __launch_bounds__(256) void gates_kernel(
    const float* __restrict__ x, const float* __restrict__ Wg,
    const float* __restrict__ Wgb, u16* __restrict__ Z)
{
    const int row = blockIdx.x;
    const int tid = threadIdx.x;
    const int k = tid * 8;
    const float* xr = x + (size_t)row * 2048;
    u16* zr = Z + (size_t)row * 6144;

    float xv[8], sv[8], dv[8];
    load8f(xv, xr + k);
    load8b(sv, zr + 2048 + k);
    load8b(dv, zr + 4096 + k);

    float p[3];
    #pragma unroll
    for (int gg = 0; gg < 3; ++gg) {
        float wx[8], ws[8], wd[8];
        load8f(wx, Wg + gg * 6144 + k);
        load8f(ws, Wg + gg * 6144 + 2048 + k);
        load8f(wd, Wg + gg * 6144 + 4096 + k);
        float acc = 0.f;
        #pragma unroll
        for (int j = 0; j < 8; ++j)
            acc += xv[j] * wx[j] + sv[j] * ws[j] + dv[j] * wd[j];
        p[gg] = acc;
    }

    #pragma unroll
    for (int off = 32; off > 0; off >>= 1) {
        p[0] += __shfl_down(p[0], off);
        p[1] += __shfl_down(p[1], off);
        p[2] += __shfl_down(p[2], off);
    }

    __shared__ float red[4][3];
    __shared__ float gsh[3];
    int wv = tid >> 6, lane = tid & 63;
    if (lane == 0) { red[wv][0] = p[0]; red[wv][1] = p[1]; red[wv][2] = p[2]; }
    __syncthreads();
    if (tid == 0) {
        float l0 = red[0][0] + red[1][0] + red[2][0] + red[3][0] + Wgb[0];
        float l1 = red[0][1] + red[1][1] + red[2][1] + red[3][1] + Wgb[1];
        float l2 = red[0][2] + red[1][2] + red[2][2] + red[3][2] + Wgb[2];
        float m = fmaxf(l0, fmaxf(l1, l2));
        float e0 = __expf(l0 - m), e1 = __expf(l1 - m), e2 = __expf(l2 - m);
        float inv = 1.f / (e0 + e1 + e2);
        gsh[0] = e0 * inv; gsh[1] = e1 * inv; gsh[2] = e2 * inv;
    }
    __syncthreads();
    float g0 = gsh[0], g1 = gsh[1], g2 = gsh[2];
    store8b(zr + k, xv, g0);
    store8b(zr + 2048 + k, sv, g1);
    store8b(zr + 4096 + k, dv, g2);
}

// ---------------------------------------------------------------------------
// Kernel 3: Y(8192x2048) = Z(8192x6144) @ Wcat^T + bias.  bf16 MFMA,
// m97 structure: 128x128 tile, BK=32, global_load_lds width 16,
// 4 waves x (4x4) 16x16x32 tiles. Output fp32.
// ---------------------------------------------------------------------------
__global__ __launch_bounds__(256) void gemm_kernel(
    const u16* __restrict__ Z, const u16* __restrict__ Wcat,
    const float* __restrict__ bias, float* __restrict__ out)
{
    __shared__ u16 a_sh[128 * 32];
    __shared__ u16 b_sh[128 * 32];

    const int tid = threadIdx.x;
    const int bm = blockIdx.y * 128;
    const int bn = blockIdx.x * 128;

    const int srow = tid >> 2;           // 0..63
    const int ssub = (tid & 3) * 8;      // 0,8,16,24
    const u16* aglob = Z + (size_t)(bm + srow) * 6144 + ssub;
    const u16* bglob = Wcat + (size_t)(bn + srow) * 6144 + ssub;
    u16* alds0 = a_sh + tid * 8;
    u16* alds1 = a_sh + (tid + 256) * 8;
    u16* blds0 = b_sh + tid * 8;
    u16* blds1 = b_sh + (tid + 256) * 8;

    const int lane = tid & 63;
    const int wv = tid >> 6;
    const int wm = (wv & 1) * 64;
    const int wn = (wv >> 1) * 64;
    const int fr = lane & 15;
    const int fq = lane >> 4;

    f32x4 acc[4][4] = {};

    for (int kt = 0; kt < 192; ++kt) {
        const int k0 = kt * 32;
        const u16* ag = aglob + k0;
        const u16* bg = bglob + k0;

        __builtin_amdgcn_global_load_lds((const GAS uint32_t*)ag,
                                         (LAS uint32_t*)alds0, 16, 0, 0);
        __builtin_amdgcn_global_load_lds((const GAS uint32_t*)(ag + (size_t)64 * 6144),
                                         (LAS uint32_t*)alds1, 16, 0, 0);
        __builtin_amdgcn_global_load_lds((const GAS uint32_t*)bg,
                                         (LAS uint32_t*)blds0, 16, 0, 0);
        __builtin_amdgcn_global_load_lds((const GAS uint32_t*)(bg + (size_t)64 * 6144),
                                         (LAS uint32_t*)blds1, 16, 0, 0);
        __syncthreads();

        bf16x8 avf[4], bvf[4];
        #pragma unroll
        for (int i = 0; i < 4; ++i)
            avf[i] = *(const bf16x8*)(a_sh + (wm + i * 16 + fr) * 32 + fq * 8);
        #pragma unroll
        for (int j = 0; j < 4; ++j)
            bvf[j] = *(const bf16x8*)(b_sh + (wn + j * 16 + fr) * 32 + fq * 8);
        #pragma unroll
        for (int i = 0; i < 4; ++i)
            #pragma unroll
            for (int j = 0; j < 4; ++j)
                acc[i][j] = __builtin_amdgcn_mfma_f32_16x16x32_bf16(
                    avf[i], bvf[j], acc[i][j], 0, 0, 0);
        __syncthreads();
    }

    #pragma unroll
    for (int j = 0; j < 4; ++j) {
        const int col = bn + wn + j * 16 + fr;
        const float bv = bias[col];
        #pragma unroll
        for (int i = 0; i < 4; ++i) {
            const int row0 = bm + wm + i * 16 + fq * 4;
            #pragma unroll
            for (int r = 0; r < 4; ++r)
                out[(size_t)(row0 + r) * 2048 + col] = acc[i][j][r] + bv;
        }
    }
}

extern "C" void kernel_launch(void* const* d_in, const int* in_sizes, int n_in,
                              void* d_out, int out_size, void* d_ws, size_t ws_size,
                              hipStream_t stream) {
    const float* x    = (const float*)d_in[0];
    const float* Wp   = (const float*)d_in[1];
    const float* Wi   = (const float*)d_in[2];
    const float* Wd   = (const float*)d_in[3];
    const float* al   = (const float*)d_in[4];
    const float* bl   = (const float*)d_in[5];
    const float* Wg   = (const float*)d_in[6];
    const float* Wgb  = (const float*)d_in[7];
    const float* bias = (const float*)d_in[8];
    float* out = (float*)d_out;

    u16* Z    = (u16*)d_ws;                                   // 96 MB
    u16* Wcat = (u16*)((char*)d_ws + (size_t)8192 * 6144 * 2); // +24 MB

    pack_w<<<6144, 256, 0, stream>>>(Wp, Wi, Wd, Wcat);
    scan_kernel<<<128, 64, 0, stream>>>(x, al, bl, Z);
    gates_kernel<<<8192, 256, 0, stream>>>(x, Wg, Wgb, Z);
    gemm_kernel<<<dim3(16, 64), 256, 0, stream>>>(Z, Wcat, bias, out);
}

// Round 3
// 521.147 us; speedup vs baseline: 1.3644x; 1.3644x over previous
//
#include <hip/hip_runtime.h>
#include <stdint.h>

typedef unsigned short u16;

#define GAS __attribute__((address_space(1)))
#define LAS __attribute__((address_space(3)))

typedef __bf16 bf16x8 __attribute__((ext_vector_type(8)));
typedef float f32x4 __attribute__((ext_vector_type(4)));

// B=4, T=2048, D_IN=D_OUT=2048. M = 8192, K = 6144, N = 2048.
// All inputs/outputs fp32. GEMM internally bf16 MFMA.
// ws layout: Z bf16 [8192 x 6144] (96 MB) | Wcat bf16 [2048 x 6144] (24 MB)
// Scan carries (2 MB) are tucked into Z's segment-0 region (rows 0..511,
// first 4096 B of each row) — free until gates_kernel overwrites seg0 later.

__device__ inline u16 f2b(float f) {
    uint32_t x = __float_as_uint(f);
    uint32_t r = (x + 0x7fffu + ((x >> 16) & 1u)) >> 16;
    return (u16)r;
}

__device__ inline float b2f(u16 u) {
    union { uint32_t i; float f; } v;
    v.i = ((uint32_t)u) << 16;
    return v.f;
}

__device__ inline void load8b(float* v, const u16* p) {
    uint4 u = *(const uint4*)p;
    v[0] = b2f((u16)(u.x)); v[1] = b2f((u16)(u.x >> 16));
    v[2] = b2f((u16)(u.y)); v[3] = b2f((u16)(u.y >> 16));
    v[4] = b2f((u16)(u.z)); v[5] = b2f((u16)(u.z >> 16));
    v[6] = b2f((u16)(u.w)); v[7] = b2f((u16)(u.w >> 16));
}

__device__ inline void load8f(float* v, const float* p) {
    float4 a = *(const float4*)p;
    float4 b = *(const float4*)(p + 4);
    v[0] = a.x; v[1] = a.y; v[2] = a.z; v[3] = a.w;
    v[4] = b.x; v[5] = b.y; v[6] = b.z; v[7] = b.w;
}

__device__ inline void store8b(u16* p, const float* v, float scale) {
    uint4 u;
    u.x = (uint32_t)f2b(v[0] * scale) | ((uint32_t)f2b(v[1] * scale) << 16);
    u.y = (uint32_t)f2b(v[2] * scale) | ((uint32_t)f2b(v[3] * scale) << 16);
    u.z = (uint32_t)f2b(v[4] * scale) | ((uint32_t)f2b(v[5] * scale) << 16);
    u.w = (uint32_t)f2b(v[6] * scale) | ((uint32_t)f2b(v[7] * scale) << 16);
    *(uint4*)p = u;
}

__device__ inline float sigmoidf(float v) { return 1.f / (1.f + __expf(-v)); }

__device__ inline float pow64f(float a) {
    float p = a * a;   // ^2
    p = p * p;         // ^4
    p = p * p;         // ^8
    p = p * p;         // ^16
    p = p * p;         // ^32
    return p * p;      // ^64
}

// Carry scratch inside Z seg0: plane 0 = s, plane 1 = d.
__device__ inline float* carry_ptr(u16* Z, int plane, int b, int c, int d) {
    int f = ((plane * 4 + b) * 32 + c) * 2048 + d;   // < 524288
    int row = f >> 10;                               // 1024 floats per row seg0
    int off = f & 1023;
    return (float*)(Z + (size_t)row * 6144) + off;
}

// ---------------------------------------------------------------------------
// Kernel 0: pack Wp|Wi|Wd (fp32) into Wcat bf16 rows of 6144.
// ---------------------------------------------------------------------------
__global__ __launch_bounds__(256) void pack_w(
    const float* __restrict__ Wp, const float* __restrict__ Wi,
    const float* __restrict__ Wd, u16* __restrict__ Wcat)
{
    int i = (blockIdx.x * 256 + threadIdx.x) * 8;
    int seg = i >> 22;
    int j = i & 4194303;
    const float* src = (seg == 0) ? Wp : (seg == 1) ? Wi : Wd;
    int o = j >> 11;
    int c = j & 2047;
    float v[8];
    load8f(v, src + j);
    store8b(Wcat + (size_t)o * 6144 + seg * 2048 + c, v, 1.0f);
}

// ---------------------------------------------------------------------------
// Scan pass 1: per (b, chunk, d) local scan of 64 steps with zero carry;
// store local end states. grid (8, 32, 4), block 256.
// ---------------------------------------------------------------------------
__global__ __launch_bounds__(256) void scan_pass1(
    const float* __restrict__ x, const float* __restrict__ alog,
    const float* __restrict__ blog, u16* __restrict__ Z)
{
    const int d = blockIdx.x * 256 + threadIdx.x;
    const int c = blockIdx.y;
    const int b = blockIdx.z;
    const float alpha = sigmoidf(alog[d]);
    const float beta  = sigmoidf(blog[d]);
    const float oma = 1.f - alpha, omb = 1.f - beta;
    const float* xp = x + ((size_t)b * 2048 + c * 64) * 2048 + d;
    float xprev = (c == 0) ? 0.f : xp[-2048];
    float s = 0.f, dd = 0.f;
    #pragma unroll 8
    for (int t = 0; t < 64; ++t) {
        float xf = xp[(size_t)t * 2048];
        s = alpha * s + oma * xf;
        dd = beta * dd + omb * (xf - xprev);
        xprev = xf;
    }
    *carry_ptr(Z, 0, b, c, d) = s;
    *carry_ptr(Z, 1, b, c, d) = dd;
}

// ---------------------------------------------------------------------------
// Scan pass 2: serial combine over 32 chunks per (b,d); convert local-end
// states into input carries. 32 blocks x 256.
// ---------------------------------------------------------------------------
__global__ __launch_bounds__(256) void scan_pass2(
    const float* __restrict__ alog, const float* __restrict__ blog,
    u16* __restrict__ Z)
{
    const int g = blockIdx.x * 256 + threadIdx.x;   // 0..8191
    const int b = g >> 11;
    const int d = g & 2047;
    const float aL = pow64f(sigmoidf(alog[d]));
    const float bL = pow64f(sigmoidf(blog[d]));
    float sIn = 0.f, dIn = 0.f;
    for (int c = 0; c < 32; ++c) {
        float* sp = carry_ptr(Z, 0, b, c, d);
        float* dp = carry_ptr(Z, 1, b, c, d);
        float sl = *sp, dl = *dp;
        *sp = sIn; *dp = dIn;
        sIn = sl + aL * sIn;
        dIn = dl + bL * dIn;
    }
}

// ---------------------------------------------------------------------------
// Scan pass 3: exact scan per chunk starting from input carry; write bf16
// s,d into Z segments 1,2. grid (8, 32, 4), block 256.
// ---------------------------------------------------------------------------
__global__ __launch_bounds__(256) void scan_pass3(
    const float* __restrict__ x, const float* __restrict__ alog,
    const float* __restrict__ blog, u16* __restrict__ Z)
{
    const int d = blockIdx.x * 256 + threadIdx.x;
    const int c = blockIdx.y;
    const int b = blockIdx.z;
    const float alpha = sigmoidf(alog[d]);
    const float beta  = sigmoidf(blog[d]);
    const float oma = 1.f - alpha, omb = 1.f - beta;
    const float* xp = x + ((size_t)b * 2048 + c * 64) * 2048 + d;
    u16* zp = Z + ((size_t)b * 2048 + c * 64) * 6144 + 2048 + d;
    float s  = *carry_ptr(Z, 0, b, c, d);
    float dd = *carry_ptr(Z, 1, b, c, d);
    float xprev = (c == 0) ? 0.f : xp[-2048];
    #pragma unroll 8
    for (int t = 0; t < 64; ++t) {
        float xf = xp[(size_t)t * 2048];
        s = alpha * s + oma * xf;
        dd = beta * dd + omb * (xf - xprev);
        xprev = xf;
        size_t zo = (size_t)t * 6144;
        zp[zo] = f2b(s);
        zp[zo + 2048] = f2b(dd);
    }
}

// ---------------------------------------------------------------------------
// Gates: per-row logits + softmax; write Z row = [g0*x|g1*s|g2*d] bf16.
// One block (256 thr) per row. (Overwrites seg0 carries — by then consumed.)
// ---------------------------------------------------------------------------
__global__ __launch_bounds__(256) void gates_kernel(
    const float* __restrict__ x, const float* __restrict__ Wg,
    const float* __restrict__ Wgb, u16* __restrict__ Z)
{
    const int row = blockIdx.x;
    const int tid = threadIdx.x;
    const int k = tid * 8;
    const float* xr = x + (size_t)row * 2048;
    u16* zr = Z + (size_t)row * 6144;

    float xv[8], sv[8], dv[8];
    load8f(xv, xr + k);
    load8b(sv, zr + 2048 + k);
    load8b(dv, zr + 4096 + k);

    float p[3];
    #pragma unroll
    for (int gg = 0; gg < 3; ++gg) {
        float wx[8], ws[8], wd[8];
        load8f(wx, Wg + gg * 6144 + k);
        load8f(ws, Wg + gg * 6144 + 2048 + k);
        load8f(wd, Wg + gg * 6144 + 4096 + k);
        float acc = 0.f;
        #pragma unroll
        for (int j = 0; j < 8; ++j)
            acc += xv[j] * wx[j] + sv[j] * ws[j] + dv[j] * wd[j];
        p[gg] = acc;
    }

    #pragma unroll
    for (int off = 32; off > 0; off >>= 1) {
        p[0] += __shfl_down(p[0], off);
        p[1] += __shfl_down(p[1], off);
        p[2] += __shfl_down(p[2], off);
    }

    __shared__ float red[4][3];
    __shared__ float gsh[3];
    int wv = tid >> 6, lane = tid & 63;
    if (lane == 0) { red[wv][0] = p[0]; red[wv][1] = p[1]; red[wv][2] = p[2]; }
    __syncthreads();
    if (tid == 0) {
        float l0 = red[0][0] + red[1][0] + red[2][0] + red[3][0] + Wgb[0];
        float l1 = red[0][1] + red[1][1] + red[2][1] + red[3][1] + Wgb[1];
        float l2 = red[0][2] + red[1][2] + red[2][2] + red[3][2] + Wgb[2];
        float m = fmaxf(l0, fmaxf(l1, l2));
        float e0 = __expf(l0 - m), e1 = __expf(l1 - m), e2 = __expf(l2 - m);
        float inv = 1.f / (e0 + e1 + e2);
        gsh[0] = e0 * inv; gsh[1] = e1 * inv; gsh[2] = e2 * inv;
    }
    __syncthreads();
    float g0 = gsh[0], g1 = gsh[1], g2 = gsh[2];
    store8b(zr + k, xv, g0);
    store8b(zr + 2048 + k, sv, g1);
    store8b(zr + 4096 + k, dv, g2);
}

// ---------------------------------------------------------------------------
// GEMM: Y(8192x2048) = Z(8192x6144) @ Wcat^T + bias.  bf16 MFMA, 128x128
// tile, BK=32, global_load_lds width 16, 4 waves x (4x4) 16x16x32 tiles.
// LDS bank-conflict fix: XOR swizzle. LDS chunk (row, cq) holds global
// 8-elem sub-chunk q = cq ^ ((row>>1)&3). Staging permutes the global
// source per lane (LDS dest must stay lane-contiguous for global_load_lds);
// readers index with qsw = (fq ^ ((fr>>1)&3)) so each 16-lane quarter-wave
// covers all 8 bank groups exactly twice (2-way = free, m136).
// ---------------------------------------------------------------------------
__global__ __launch_bounds__(256) void gemm_kernel(
    const u16* __restrict__ Z, const u16* __restrict__ Wcat,
    const float* __restrict__ bias, float* __restrict__ out)
{
    __shared__ u16 a_sh[128 * 32];
    __shared__ u16 b_sh[128 * 32];

    const int tid = threadIdx.x;
    const int bm = blockIdx.y * 128;
    const int bn = blockIdx.x * 128;

    const int srow = tid >> 2;                        // 0..63
    const int scq  = tid & 3;                         // LDS chunk-in-row
    const int ssub = (scq ^ ((srow >> 1) & 3)) * 8;   // swizzled global sub
    const u16* aglob = Z + (size_t)(bm + srow) * 6144 + ssub;
    const u16* bglob = Wcat + (size_t)(bn + srow) * 6144 + ssub;
    u16* alds0 = a_sh + tid * 8;
    u16* alds1 = a_sh + (tid + 256) * 8;
    u16* blds0 = b_sh + tid * 8;
    u16* blds1 = b_sh + (tid + 256) * 8;

    const int lane = tid & 63;
    const int wv = tid >> 6;
    const int wm = (wv & 1) * 64;
    const int wn = (wv >> 1) * 64;
    const int fr = lane & 15;
    const int fq = lane >> 4;
    const int qsw = (fq ^ ((fr >> 1) & 3)) * 8;       // swizzled read sub

    f32x4 acc[4][4] = {};

    for (int kt = 0; kt < 192; ++kt) {
        const int k0 = kt * 32;
        const u16* ag = aglob + k0;
        const u16* bg = bglob + k0;

        __builtin_amdgcn_global_load_lds((const GAS uint32_t*)ag,
                                         (LAS uint32_t*)alds0, 16, 0, 0);
        __builtin_amdgcn_global_load_lds((const GAS uint32_t*)(ag + (size_t)64 * 6144),
                                         (LAS uint32_t*)alds1, 16, 0, 0);
        __builtin_amdgcn_global_load_lds((const GAS uint32_t*)bg,
                                         (LAS uint32_t*)blds0, 16, 0, 0);
        __builtin_amdgcn_global_load_lds((const GAS uint32_t*)(bg + (size_t)64 * 6144),
                                         (LAS uint32_t*)blds1, 16, 0, 0);
        __syncthreads();

        bf16x8 avf[4], bvf[4];
        #pragma unroll
        for (int i = 0; i < 4; ++i)
            avf[i] = *(const bf16x8*)(a_sh + (wm + i * 16 + fr) * 32 + qsw);
        #pragma unroll
        for (int j = 0; j < 4; ++j)
            bvf[j] = *(const bf16x8*)(b_sh + (wn + j * 16 + fr) * 32 + qsw);
        #pragma unroll
        for (int i = 0; i < 4; ++i)
            #pragma unroll
            for (int j = 0; j < 4; ++j)
                acc[i][j] = __builtin_amdgcn_mfma_f32_16x16x32_bf16(
                    avf[i], bvf[j], acc[i][j], 0, 0, 0);
        __syncthreads();
    }

    #pragma unroll
    for (int j = 0; j < 4; ++j) {
        const int col = bn + wn + j * 16 + fr;
        const float bv = bias[col];
        #pragma unroll
        for (int i = 0; i < 4; ++i) {
            const int row0 = bm + wm + i * 16 + fq * 4;
            #pragma unroll
            for (int r = 0; r < 4; ++r)
                out[(size_t)(row0 + r) * 2048 + col] = acc[i][j][r] + bv;
        }
    }
}

extern "C" void kernel_launch(void* const* d_in, const int* in_sizes, int n_in,
                              void* d_out, int out_size, void* d_ws, size_t ws_size,
                              hipStream_t stream) {
    const float* x    = (const float*)d_in[0];
    const float* Wp   = (const float*)d_in[1];
    const float* Wi   = (const float*)d_in[2];
    const float* Wd   = (const float*)d_in[3];
    const float* al   = (const float*)d_in[4];
    const float* bl   = (const float*)d_in[5];
    const float* Wg   = (const float*)d_in[6];
    const float* Wgb  = (const float*)d_in[7];
    const float* bias = (const float*)d_in[8];
    float* out = (float*)d_out;

    u16* Z    = (u16*)d_ws;                                    // 96 MB
    u16* Wcat = (u16*)((char*)d_ws + (size_t)8192 * 6144 * 2); // +24 MB

    pack_w<<<6144, 256, 0, stream>>>(Wp, Wi, Wd, Wcat);
    scan_pass1<<<dim3(8, 32, 4), 256, 0, stream>>>(x, al, bl, Z);
    scan_pass2<<<32, 256, 0, stream>>>(al, bl, Z);
    scan_pass3<<<dim3(8, 32, 4), 256, 0, stream>>>(x, al, bl, Z);
    gates_kernel<<<8192, 256, 0, stream>>>(x, Wg, Wgb, Z);
    gemm_kernel<<<dim3(16, 64), 256, 0, stream>>>(Z, Wcat, bias, out);
}

// Round 4
// 442.718 us; speedup vs baseline: 1.6061x; 1.1772x over previous
//
#include <hip/hip_runtime.h>
#include <stdint.h>

typedef unsigned short u16;

#define GAS __attribute__((address_space(1)))
#define LAS __attribute__((address_space(3)))

typedef __bf16 bf16x8 __attribute__((ext_vector_type(8)));
typedef float f32x4 __attribute__((ext_vector_type(4)));

// B=4, T=2048, D_IN=D_OUT=2048. M = 8192, K = 6144, N = 2048.
// All inputs/outputs fp32. GEMM internally bf16 MFMA.
// ws layout: Z bf16 [8192 x 6144] (96 MB) | Wcat bf16 [2048 x 6144] (24 MB)
// Scan carries (2 MB) live in Z seg0 (overwritten later by gates_kernel).

__device__ inline u16 f2b(float f) {
    uint32_t x = __float_as_uint(f);
    uint32_t r = (x + 0x7fffu + ((x >> 16) & 1u)) >> 16;
    return (u16)r;
}

__device__ inline float b2f(u16 u) {
    union { uint32_t i; float f; } v;
    v.i = ((uint32_t)u) << 16;
    return v.f;
}

__device__ inline void load8b(float* v, const u16* p) {
    uint4 u = *(const uint4*)p;
    v[0] = b2f((u16)(u.x)); v[1] = b2f((u16)(u.x >> 16));
    v[2] = b2f((u16)(u.y)); v[3] = b2f((u16)(u.y >> 16));
    v[4] = b2f((u16)(u.z)); v[5] = b2f((u16)(u.z >> 16));
    v[6] = b2f((u16)(u.w)); v[7] = b2f((u16)(u.w >> 16));
}

__device__ inline void load8f(float* v, const float* p) {
    float4 a = *(const float4*)p;
    float4 b = *(const float4*)(p + 4);
    v[0] = a.x; v[1] = a.y; v[2] = a.z; v[3] = a.w;
    v[4] = b.x; v[5] = b.y; v[6] = b.z; v[7] = b.w;
}

__device__ inline void store8b(u16* p, const float* v, float scale) {
    uint4 u;
    u.x = (uint32_t)f2b(v[0] * scale) | ((uint32_t)f2b(v[1] * scale) << 16);
    u.y = (uint32_t)f2b(v[2] * scale) | ((uint32_t)f2b(v[3] * scale) << 16);
    u.z = (uint32_t)f2b(v[4] * scale) | ((uint32_t)f2b(v[5] * scale) << 16);
    u.w = (uint32_t)f2b(v[6] * scale) | ((uint32_t)f2b(v[7] * scale) << 16);
    *(uint4*)p = u;
}

__device__ inline float sigmoidf(float v) { return 1.f / (1.f + __expf(-v)); }

__device__ inline float pow64f(float a) {
    float p = a * a;
    p = p * p;
    p = p * p;
    p = p * p;
    p = p * p;
    return p * p;
}

__device__ inline float* carry_ptr(u16* Z, int plane, int b, int c, int d) {
    int f = ((plane * 4 + b) * 32 + c) * 2048 + d;
    int row = f >> 10;
    int off = f & 1023;
    return (float*)(Z + (size_t)row * 6144) + off;
}

// ---------------------------------------------------------------------------
// pack Wp|Wi|Wd (fp32) into Wcat bf16 rows of 6144.
// ---------------------------------------------------------------------------
__global__ __launch_bounds__(256) void pack_w(
    const float* __restrict__ Wp, const float* __restrict__ Wi,
    const float* __restrict__ Wd, u16* __restrict__ Wcat)
{
    int i = (blockIdx.x * 256 + threadIdx.x) * 8;
    int seg = i >> 22;
    int j = i & 4194303;
    const float* src = (seg == 0) ? Wp : (seg == 1) ? Wi : Wd;
    int o = j >> 11;
    int c = j & 2047;
    float v[8];
    load8f(v, src + j);
    store8b(Wcat + (size_t)o * 6144 + seg * 2048 + c, v, 1.0f);
}

// ---------------------------------------------------------------------------
// Scan pass 1: local 64-step scans, zero carry; store end states.
// ---------------------------------------------------------------------------
__global__ __launch_bounds__(256) void scan_pass1(
    const float* __restrict__ x, const float* __restrict__ alog,
    const float* __restrict__ blog, u16* __restrict__ Z)
{
    const int d = blockIdx.x * 256 + threadIdx.x;
    const int c = blockIdx.y;
    const int b = blockIdx.z;
    const float alpha = sigmoidf(alog[d]);
    const float beta  = sigmoidf(blog[d]);
    const float oma = 1.f - alpha, omb = 1.f - beta;
    const float* xp = x + ((size_t)b * 2048 + c * 64) * 2048 + d;
    float xprev = (c == 0) ? 0.f : xp[-2048];
    float s = 0.f, dd = 0.f;
    #pragma unroll 8
    for (int t = 0; t < 64; ++t) {
        float xf = xp[(size_t)t * 2048];
        s = alpha * s + oma * xf;
        dd = beta * dd + omb * (xf - xprev);
        xprev = xf;
    }
    *carry_ptr(Z, 0, b, c, d) = s;
    *carry_ptr(Z, 1, b, c, d) = dd;
}

// ---------------------------------------------------------------------------
// Scan pass 2: combine 32 chunk carries per (b,d).
// ---------------------------------------------------------------------------
__global__ __launch_bounds__(256) void scan_pass2(
    const float* __restrict__ alog, const float* __restrict__ blog,
    u16* __restrict__ Z)
{
    const int g = blockIdx.x * 256 + threadIdx.x;
    const int b = g >> 11;
    const int d = g & 2047;
    const float aL = pow64f(sigmoidf(alog[d]));
    const float bL = pow64f(sigmoidf(blog[d]));
    float sIn = 0.f, dIn = 0.f;
    for (int c = 0; c < 32; ++c) {
        float* sp = carry_ptr(Z, 0, b, c, d);
        float* dp = carry_ptr(Z, 1, b, c, d);
        float sl = *sp, dl = *dp;
        *sp = sIn; *dp = dIn;
        sIn = sl + aL * sIn;
        dIn = dl + bL * dIn;
    }
}

// ---------------------------------------------------------------------------
// Scan pass 3: exact scan per chunk from carry; write bf16 s,d to Z.
// ---------------------------------------------------------------------------
__global__ __launch_bounds__(256) void scan_pass3(
    const float* __restrict__ x, const float* __restrict__ alog,
    const float* __restrict__ blog, u16* __restrict__ Z)
{
    const int d = blockIdx.x * 256 + threadIdx.x;
    const int c = blockIdx.y;
    const int b = blockIdx.z;
    const float alpha = sigmoidf(alog[d]);
    const float beta  = sigmoidf(blog[d]);
    const float oma = 1.f - alpha, omb = 1.f - beta;
    const float* xp = x + ((size_t)b * 2048 + c * 64) * 2048 + d;
    u16* zp = Z + ((size_t)b * 2048 + c * 64) * 6144 + 2048 + d;
    float s  = *carry_ptr(Z, 0, b, c, d);
    float dd = *carry_ptr(Z, 1, b, c, d);
    float xprev = (c == 0) ? 0.f : xp[-2048];
    #pragma unroll 8
    for (int t = 0; t < 64; ++t) {
        float xf = xp[(size_t)t * 2048];
        s = alpha * s + oma * xf;
        dd = beta * dd + omb * (xf - xprev);
        xprev = xf;
        size_t zo = (size_t)t * 6144;
        zp[zo] = f2b(s);
        zp[zo + 2048] = f2b(dd);
    }
}

// ---------------------------------------------------------------------------
// Gates: per-row logits + softmax; write Z row = [g0*x|g1*s|g2*d] bf16.
// ---------------------------------------------------------------------------
__global__ __launch_bounds__(256) void gates_kernel(
    const float* __restrict__ x, const float* __restrict__ Wg,
    const float* __restrict__ Wgb, u16* __restrict__ Z)
{
    const int row = blockIdx.x;
    const int tid = threadIdx.x;
    const int k = tid * 8;
    const float* xr = x + (size_t)row * 2048;
    u16* zr = Z + (size_t)row * 6144;

    float xv[8], sv[8], dv[8];
    load8f(xv, xr + k);
    load8b(sv, zr + 2048 + k);
    load8b(dv, zr + 4096 + k);

    float p[3];
    #pragma unroll
    for (int gg = 0; gg < 3; ++gg) {
        float wx[8], ws[8], wd[8];
        load8f(wx, Wg + gg * 6144 + k);
        load8f(ws, Wg + gg * 6144 + 2048 + k);
        load8f(wd, Wg + gg * 6144 + 4096 + k);
        float acc = 0.f;
        #pragma unroll
        for (int j = 0; j < 8; ++j)
            acc += xv[j] * wx[j] + sv[j] * ws[j] + dv[j] * wd[j];
        p[gg] = acc;
    }

    #pragma unroll
    for (int off = 32; off > 0; off >>= 1) {
        p[0] += __shfl_down(p[0], off);
        p[1] += __shfl_down(p[1], off);
        p[2] += __shfl_down(p[2], off);
    }

    __shared__ float red[4][3];
    __shared__ float gsh[3];
    int wv = tid >> 6, lane = tid & 63;
    if (lane == 0) { red[wv][0] = p[0]; red[wv][1] = p[1]; red[wv][2] = p[2]; }
    __syncthreads();
    if (tid == 0) {
        float l0 = red[0][0] + red[1][0] + red[2][0] + red[3][0] + Wgb[0];
        float l1 = red[0][1] + red[1][1] + red[2][1] + red[3][1] + Wgb[1];
        float l2 = red[0][2] + red[1][2] + red[2][2] + red[3][2] + Wgb[2];
        float m = fmaxf(l0, fmaxf(l1, l2));
        float e0 = __expf(l0 - m), e1 = __expf(l1 - m), e2 = __expf(l2 - m);
        float inv = 1.f / (e0 + e1 + e2);
        gsh[0] = e0 * inv; gsh[1] = e1 * inv; gsh[2] = e2 * inv;
    }
    __syncthreads();
    float g0 = gsh[0], g1 = gsh[1], g2 = gsh[2];
    store8b(zr + k, xv, g0);
    store8b(zr + 2048 + k, sv, g1);
    store8b(zr + 4096 + k, dv, g2);
}

// ---------------------------------------------------------------------------
// GEMM: Y(8192x2048) = Z(8192x6144) @ Wcat^T + bias.  bf16 MFMA, 128x128
// tile, BK=64 (two 16x16x32 half-steps per LDS tile), 96 K-iterations ->
// half the barrier drains of BK=32. 8 outstanding global_load_lds (16B)
// per barrier. __launch_bounds__(256,3) pins 3 waves/EU so 3 blocks/CU
// stay co-resident (m132's BK=128 lost this and regressed).
// Swizzle: LDS chunk cq of row r holds global 16B chunk cq ^ (r&7);
// readers use (fq + 4h) ^ (fr&7) -> quarter-wave covers all 8 bank groups
// 2-way (free, m136).
// ---------------------------------------------------------------------------
__global__ __launch_bounds__(256, 3) void gemm_kernel(
    const u16* __restrict__ Z, const u16* __restrict__ Wcat,
    const float* __restrict__ bias, float* __restrict__ out)
{
    __shared__ u16 a_sh[128 * 64];
    __shared__ u16 b_sh[128 * 64];

    const int tid = threadIdx.x;
    const int bm = blockIdx.y * 128;
    const int bn = blockIdx.x * 128;

    // staging: 8 threads per 64-elem row; each call covers 32 rows.
    const int srow = tid >> 3;                       // 0..31
    const int scq  = tid & 7;                        // LDS chunk in row
    const int ssub = (scq ^ (srow & 7)) * 8;         // swizzled global chunk
    const u16* aglob = Z + (size_t)(bm + srow) * 6144 + ssub;
    const u16* bglob = Wcat + (size_t)(bn + srow) * 6144 + ssub;
    u16* alds[4];
    u16* blds[4];
    #pragma unroll
    for (int c = 0; c < 4; ++c) {
        alds[c] = a_sh + c * 2048 + tid * 8;
        blds[c] = b_sh + c * 2048 + tid * 8;
    }

    const int lane = tid & 63;
    const int wv = tid >> 6;
    const int wm = (wv & 1) * 64;
    const int wn = (wv >> 1) * 64;
    const int fr = lane & 15;
    const int fq = lane >> 4;

    f32x4 acc[4][4] = {};

    for (int kt = 0; kt < 96; ++kt) {
        const int k0 = kt * 64;
        #pragma unroll
        for (int c = 0; c < 4; ++c)
            __builtin_amdgcn_global_load_lds(
                (const GAS uint32_t*)(aglob + (size_t)c * 32 * 6144 + k0),
                (LAS uint32_t*)alds[c], 16, 0, 0);
        #pragma unroll
        for (int c = 0; c < 4; ++c)
            __builtin_amdgcn_global_load_lds(
                (const GAS uint32_t*)(bglob + (size_t)c * 32 * 6144 + k0),
                (LAS uint32_t*)blds[c], 16, 0, 0);
        __syncthreads();

        #pragma unroll
        for (int h = 0; h < 2; ++h) {
            bf16x8 avf[4], bvf[4];
            #pragma unroll
            for (int i = 0; i < 4; ++i) {
                int row = wm + i * 16 + fr;
                int ch = (fq + 4 * h) ^ (row & 7);
                avf[i] = *(const bf16x8*)(a_sh + row * 64 + ch * 8);
            }
            #pragma unroll
            for (int j = 0; j < 4; ++j) {
                int row = wn + j * 16 + fr;
                int ch = (fq + 4 * h) ^ (row & 7);
                bvf[j] = *(const bf16x8*)(b_sh + row * 64 + ch * 8);
            }
            #pragma unroll
            for (int i = 0; i < 4; ++i)
                #pragma unroll
                for (int j = 0; j < 4; ++j)
                    acc[i][j] = __builtin_amdgcn_mfma_f32_16x16x32_bf16(
                        avf[i], bvf[j], acc[i][j], 0, 0, 0);
        }
        __syncthreads();
    }

    #pragma unroll
    for (int j = 0; j < 4; ++j) {
        const int col = bn + wn + j * 16 + fr;
        const float bv = bias[col];
        #pragma unroll
        for (int i = 0; i < 4; ++i) {
            const int row0 = bm + wm + i * 16 + fq * 4;
            #pragma unroll
            for (int r = 0; r < 4; ++r)
                out[(size_t)(row0 + r) * 2048 + col] = acc[i][j][r] + bv;
        }
    }
}

extern "C" void kernel_launch(void* const* d_in, const int* in_sizes, int n_in,
                              void* d_out, int out_size, void* d_ws, size_t ws_size,
                              hipStream_t stream) {
    const float* x    = (const float*)d_in[0];
    const float* Wp   = (const float*)d_in[1];
    const float* Wi   = (const float*)d_in[2];
    const float* Wd   = (const float*)d_in[3];
    const float* al   = (const float*)d_in[4];
    const float* bl   = (const float*)d_in[5];
    const float* Wg   = (const float*)d_in[6];
    const float* Wgb  = (const float*)d_in[7];
    const float* bias = (const float*)d_in[8];
    float* out = (float*)d_out;

    u16* Z    = (u16*)d_ws;                                    // 96 MB
    u16* Wcat = (u16*)((char*)d_ws + (size_t)8192 * 6144 * 2); // +24 MB

    pack_w<<<6144, 256, 0, stream>>>(Wp, Wi, Wd, Wcat);
    scan_pass1<<<dim3(8, 32, 4), 256, 0, stream>>>(x, al, bl, Z);
    scan_pass2<<<32, 256, 0, stream>>>(al, bl, Z);
    scan_pass3<<<dim3(8, 32, 4), 256, 0, stream>>>(x, al, bl, Z);
    gates_kernel<<<8192, 256, 0, stream>>>(x, Wg, Wgb, Z);
    gemm_kernel<<<dim3(16, 64), 256, 0, stream>>>(Z, Wcat, bias, out);
}